// Round 5
// baseline (315.079 us; speedup 1.0000x reference)
//
#include <hip/hip_runtime.h>
#include <math.h>

#define K_POLY   20000
#define PMAX     30
#define NUM_PTS  5
#define C_MID    112
#define C_OUT    224
#define PE_DIM   32
#define GEO_DIM  256

#define POLYS    32                      // polys per block
#define THREADS  320                     // 5 waves; 160 rows = 5 M-tiles of 32
#define ASTRIDE  120                     // A-tile c-stride (bf16 elems), breaks worst LDS aliasing
#define CHUNK_ELEMS (7*7*64*8)           // 25088 bf16 = 50176 B per B-chunk (7 k-steps x 7 n-tiles)

typedef __attribute__((ext_vector_type(8)))  short short8;
typedef __attribute__((ext_vector_type(16))) float f32x16;

__device__ inline unsigned short f2bf(float f) {
    union { float f; unsigned u; } v; v.f = f;
    return (unsigned short)((v.u + 0x7fffu + ((v.u >> 16) & 1u)) >> 16);
}

// Single fused kernel: resample + PE + conv1 (-> LDS A-tile) + conv2 MFMA (B packed
// into LDS from w2 per K-chunk) + ReLU + in-wave LayerNorm + store.
__global__ __launch_bounds__(THREADS, 1) void geo_fused(
    const float* __restrict__ geoms, const int* __restrict__ lengths,
    const float* __restrict__ w1, const float* __restrict__ b1,
    const float* __restrict__ w2, const float* __restrict__ b2,
    const float* __restrict__ gamma, const float* __restrict__ beta,
    const int* __restrict__ roi_w, const int* __restrict__ roi_h,
    float* __restrict__ out)
{
    __shared__ __align__(16) unsigned short s_A[POLYS * 7 * ASTRIDE]; // 53760 B
    __shared__ __align__(16) unsigned short s_B[CHUNK_ELEMS];         // 50176 B (aliased for prep scratch)

    // ---- prep scratch aliased into s_B (all offsets in ushort units) ----
    float* s_geo = (float*)(s_B);            // [32][30][2]  = 1920 f -> +3840
    float* s_cum = (float*)(s_B + 3840);     // [32][30]     =  960 f -> +5760
    float* s_seg = (float*)(s_B + 5760);     // [32][29]     =  928 f -> +7616
    float* s_pts = (float*)(s_B + 7616);     // [32][5][2]   =  320 f -> +8256
    float* s_w1v = (float*)(s_B + 8256);     // [112*6]      =  672 f -> +9600
    float* s_b1v = (float*)(s_B + 9600);     // [112]        =  112 f -> +9824
    int*   s_len = (int*)  (s_B + 9824);     // [32]         -> +9952  (< 25088 OK)

    const int t    = threadIdx.x;
    const int lane = t & 63;
    const int wave = t >> 6;
    const int k0   = blockIdx.x * POLYS;

    // ---- stage inputs + zero A-tile halo slots (0 and 6) ----
    {
        const float* src = geoms + (size_t)k0 * (PMAX * 2);
        for (int i = t; i < POLYS * PMAX * 2; i += THREADS) s_geo[i] = src[i];
        if (t < POLYS) s_len[t] = lengths[k0 + t];
        for (int i = t; i < C_MID * 6; i += THREADS) s_w1v[i] = w1[i];
        if (t < C_MID) s_b1v[t] = b1[t];
        for (int i = t; i < POLYS * 2 * ASTRIDE; i += THREADS) {
            int poly = i / (2 * ASTRIDE);
            int r    = i % (2 * ASTRIDE);
            int slot = (r < ASTRIDE) ? 0 : 6;
            int c    = (r < ASTRIDE) ? r : r - ASTRIDE;
            s_A[(poly * 7 + slot) * ASTRIDE + c] = 0;
        }
    }
    __syncthreads();

    // ---- per-poly seg/cum (bitwise jnp.cumsum order) ----
    if (t < POLYS) {
        int L = s_len[t];
        float cum = 0.f;
        s_cum[t * PMAX] = 0.f;
        for (int i = 0; i < PMAX - 1; ++i) {
            float seg = 0.f;
            if (i < L - 1) {
                float dx = s_geo[(t * PMAX + i + 1) * 2]     - s_geo[(t * PMAX + i) * 2];
                float dy = s_geo[(t * PMAX + i + 1) * 2 + 1] - s_geo[(t * PMAX + i) * 2 + 1];
                float sq = dx * dx + dy * dy;
                seg = (sq > 0.f) ? sqrtf(sq) : 0.f;
            }
            s_seg[t * (PMAX - 1) + i] = seg;
            cum += seg;
            s_cum[t * PMAX + i + 1] = cum;
        }
    }
    __syncthreads();

    // ---- resample: one point per thread (160 threads) ----
    const float roiw  = (float)roi_w[0], roih = (float)roi_h[0];
    const float halfx = roiw * 0.5f, halfy = roih * 0.5f;
    if (t < POLYS * NUM_PTS) {
        int poly = t / NUM_PTS, j = t % NUM_PTS;
        int L = s_len[poly];
        float total = s_cum[poly * PMAX + PMAX - 1];
        float px, py;
        if (total < 1e-6f) {
            px = s_geo[poly * PMAX * 2];
            py = s_geo[poly * PMAX * 2 + 1];
        } else {
            float target = total * (0.25f * (float)j);
            int idx = PMAX;
            for (int i = 0; i < PMAX; ++i) {
                if (s_cum[poly * PMAX + i] >= target) { idx = i; break; }
            }
            idx = max(1, min(idx, L - 1));
            float tt = (target - s_cum[poly * PMAX + idx - 1]) / (s_seg[poly * (PMAX - 1) + idx - 1] + 1e-8f);
            float x0 = s_geo[(poly * PMAX + idx - 1) * 2], y0 = s_geo[(poly * PMAX + idx - 1) * 2 + 1];
            px = x0 + tt * (s_geo[(poly * PMAX + idx) * 2]     - x0);
            py = y0 + tt * (s_geo[(poly * PMAX + idx) * 2 + 1] - y0);
        }
        float cx = (px + halfx) / roiw;
        float cy = (py + halfy) / roih;
        s_pts[(poly * NUM_PTS + j) * 2]     = cx;
        s_pts[(poly * NUM_PTS + j) * 2 + 1] = cy;
        float* co = out + (size_t)K_POLY * NUM_PTS * GEO_DIM + ((size_t)(k0 + poly) * NUM_PTS + j) * 2;
        co[0] = cx;
        co[1] = cy;
    }
    __syncthreads();

    // ---- PE: channels 0..31 straight to global ----
    for (int i = t; i < POLYS * NUM_PTS * PE_DIM; i += THREADS) {
        int poly = i / (NUM_PTS * PE_DIM);
        int r = i % (NUM_PTS * PE_DIM);
        int p = r / PE_DIM;
        int f = r % PE_DIM;
        int d = f >> 4;
        int inner = f & 15;
        int fr = inner & 7;
        int isc = inner >> 3;
        float x = s_pts[(poly * NUM_PTS + p) * 2 + d];
        float arg = x * ((float)(1 << fr) * 3.14159265358979323846f);
        float v = isc ? __cosf(arg) : __sinf(arg);
        out[((size_t)(k0 + poly) * NUM_PTS + p) * GEO_DIM + f] = v;
    }

    // ---- conv1 (2->112) + ReLU -> bf16 A-tile slots 1..5 ----
    for (int i = t; i < POLYS * NUM_PTS * C_MID; i += THREADS) {
        int poly = i / (NUM_PTS * C_MID);
        int r = i % (NUM_PTS * C_MID);
        int p = r / C_MID;
        int c = r % C_MID;
        float acc = s_b1v[c];
        const float* w = &s_w1v[c * 6];
        #pragma unroll
        for (int ch = 0; ch < 2; ++ch) {
            #pragma unroll
            for (int dk = 0; dk < 3; ++dk) {
                int pp = p + dk - 1;
                float xv = (pp >= 0 && pp < NUM_PTS) ? s_pts[(poly * NUM_PTS + pp) * 2 + ch] : 0.f;
                acc += xv * w[ch * 3 + dk];
            }
        }
        s_A[(poly * 7 + p + 1) * ASTRIDE + c] = f2bf(fmaxf(acc, 0.f));
    }
    __syncthreads();   // prep done; s_B scratch free from here

    // ---- conv2 GEMM: wave w owns M-tile w (rows w*32..w*32+31), all 7 n-tiles ----
    const int n  = lane & 31;
    const int kh = lane >> 5;
    const int rblk = wave * 32 + n;              // 0..159, always valid
    const int polyA = rblk / 5, pA = rblk - polyA * 5;
    const int apBase = (polyA * 7 + pA) * ASTRIDE + kh * 8;

    f32x16 acc[7];
    #pragma unroll
    for (int nt = 0; nt < 7; ++nt)
        #pragma unroll
        for (int i = 0; i < 16; ++i) acc[nt][i] = 0.f;

    for (int chunk = 0; chunk < 3; ++chunk) {
        // pack this K-chunk of w2 into s_B (identity with read layout below)
        for (int d = t; d < CHUNK_ELEMS; d += THREADS) {
            int j   = d & 7;
            int ln  = (d >> 3) & 63;
            int grp = d >> 9;            // 0..48 = ksl*7 + ntl
            int ntl = grp % 7;
            int ksl = grp / 7;
            int khh = ln >> 5, nn = ln & 31;
            int ks  = chunk * 7 + ksl;
            int k   = ks * 16 + khh * 8 + j;     // dk == chunk over this range
            int c   = k - chunk * C_MID;
            int o   = ntl * 32 + nn;
            s_B[d] = f2bf(w2[(o * C_MID + c) * 3 + chunk]);
        }
        __syncthreads();

        #pragma unroll
        for (int ksl = 0; ksl < 7; ++ksl) {
            int ks = chunk * 7 + ksl;
            short8 a = *(const short8*)(s_A + apBase + ks * 16 + chunk * 8);
            #pragma unroll
            for (int nt = 0; nt < 7; ++nt) {
                short8 b = *(const short8*)(s_B + (ksl * 7 + nt) * 512 + lane * 8);
                acc[nt] = __builtin_amdgcn_mfma_f32_32x32x16_bf16(a, b, acc[nt], 0, 0, 0);
            }
        }
        __syncthreads();   // protect s_B before next pack
    }

    // ---- bias + ReLU + in-wave LayerNorm + store ----
    float bias[7], g[7], be[7];
    #pragma unroll
    for (int nt = 0; nt < 7; ++nt) {
        int col = nt * 32 + n;
        bias[nt] = b2[col];
        g[nt]    = gamma[col];
        be[nt]   = beta[col];
    }
    #pragma unroll
    for (int nt = 0; nt < 7; ++nt)
        #pragma unroll
        for (int i = 0; i < 16; ++i)
            acc[nt][i] = fmaxf(acc[nt][i] + bias[nt], 0.f);

    const int base_row = blockIdx.x * (POLYS * NUM_PTS) + wave * 32;
    #pragma unroll
    for (int i = 0; i < 16; ++i) {
        float s = 0.f, q = 0.f;
        #pragma unroll
        for (int nt = 0; nt < 7; ++nt) {
            float v = acc[nt][i];
            s += v;
            q += v * v;
        }
        #pragma unroll
        for (int m = 16; m >= 1; m >>= 1) {
            s += __shfl_xor(s, m, 64);
            q += __shfl_xor(q, m, 64);
        }
        float mu  = s * (1.f / C_OUT);
        float var = fmaxf(q * (1.f / C_OUT) - mu * mu, 0.f);
        float rs  = rsqrtf(var + 1e-5f);

        int rg = base_row + (i & 3) + 8 * (i >> 2) + 4 * kh;
        size_t ob = (size_t)rg * GEO_DIM + PE_DIM + n;
        #pragma unroll
        for (int nt = 0; nt < 7; ++nt)
            out[ob + nt * 32] = (acc[nt][i] - mu) * rs * g[nt] + be[nt];
    }
}

extern "C" void kernel_launch(void* const* d_in, const int* in_sizes, int n_in,
                              void* d_out, int out_size, void* d_ws, size_t ws_size,
                              hipStream_t stream) {
    const float* geoms   = (const float*)d_in[0];
    const int*   lengths = (const int*)d_in[1];
    const float* w1      = (const float*)d_in[2];
    const float* b1      = (const float*)d_in[3];
    const float* w2      = (const float*)d_in[4];
    const float* b2      = (const float*)d_in[5];
    const float* gamma   = (const float*)d_in[6];
    const float* beta    = (const float*)d_in[7];
    const int*   roi_w   = (const int*)d_in[8];
    const int*   roi_h   = (const int*)d_in[9];
    float* out = (float*)d_out;

    hipLaunchKernelGGL(geo_fused, dim3(K_POLY / POLYS), dim3(THREADS), 0, stream,
                       geoms, lengths, w1, b1, w2, b2, gamma, beta, roi_w, roi_h, out);
}

// Round 6
// 192.780 us; speedup vs baseline: 1.6344x; 1.6344x over previous
//
#include <hip/hip_runtime.h>
#include <math.h>

#define K_POLY   20000
#define PMAX     30
#define NUM_PTS  5
#define C_MID    112
#define C_OUT    224
#define PE_DIM   32
#define GEO_DIM  256
#define M_ROWS   (K_POLY*NUM_PTS)        // 100000

#define ROWS_B   64                      // rows per block (4 waves x 16)
#define NPOLY_T  14                      // polys staged per block (covers 64 rows + spill)
#define NTILES   14                      // 224/16 n-tiles
#define KSTEPS   11                      // K padded 336 -> 352 = 11*32
#define WP_ELEMS (KSTEPS*NTILES*64*8)    // 78848 bf16 = 157696 B
#define A_SLOTS  (NPOLY_T*7 + 1)         // 99 slots of 112 (halo layout + final zero slot)

typedef __attribute__((ext_vector_type(8))) short short8;
typedef __attribute__((ext_vector_type(4))) float f32x4;

__device__ inline unsigned short f2bf(float f) {
    union { float f; unsigned u; } v; v.f = f;
    return (unsigned short)((v.u + 0x7fffu + ((v.u >> 16) & 1u)) >> 16);
}

// ---- pack w2 [224][112][3] fp32 -> bf16 16x16x32 B-fragment order, K padded to 352 ----
__global__ void pack_w2(const float* __restrict__ w2, unsigned short* __restrict__ Wp) {
    int i = blockIdx.x * 256 + threadIdx.x;
    if (i >= WP_ELEMS) return;
    int j    = i & 7;
    int lane = (i >> 3) & 63;
    int grp  = i >> 9;               // ks*14 + nt
    int nt   = grp % NTILES;
    int ks   = grp / NTILES;
    int k    = ks * 32 + (lane >> 4) * 8 + j;   // 0..351 ; k = dk*112 + c
    int n    = nt * 16 + (lane & 15);           // 0..223
    float v = 0.f;
    if (k < 336) {
        int dk = k / C_MID, c = k - dk * C_MID;
        v = w2[(n * C_MID + c) * 3 + dk];
    }
    Wp[i] = f2bf(v);
}

// ---- fused: resample + conv1 -> LDS A-tile, MFMA conv2 + ReLU + LN + PE + store ----
__global__ __launch_bounds__(256, 4) void geo_fused(
    const float* __restrict__ geoms, const int* __restrict__ lengths,
    const float* __restrict__ w1, const float* __restrict__ b1,
    const float* __restrict__ b2, const float* __restrict__ gamma,
    const float* __restrict__ beta,
    const int* __restrict__ roi_w, const int* __restrict__ roi_h,
    const unsigned short* __restrict__ Wp,
    float* __restrict__ out)
{
    __shared__ __align__(16) unsigned short s_A[A_SLOTS * C_MID];  // 11088 elems = 22176 B
    __shared__ float s_geo[NPOLY_T][PMAX][2];
    __shared__ float s_cum[NPOLY_T][PMAX];
    __shared__ float s_seg[NPOLY_T][PMAX - 1];
    __shared__ float s_pts[NPOLY_T][NUM_PTS][2];
    __shared__ float s_w1[C_MID * 6];
    __shared__ float s_b1[C_MID];
    __shared__ int   s_len[NPOLY_T];

    const int t  = threadIdx.x;
    const int r0 = blockIdx.x * ROWS_B;
    const int pb = r0 / NUM_PTS;                       // first poly staged
    const int npoly = min(NPOLY_T, K_POLY - pb);

    // ---- zero A-tile (covers halo slots, pad slot, invalid polys) ----
    {
        uint4* za = (uint4*)s_A;
        for (int i = t; i < (A_SLOTS * C_MID) / 8; i += 256) za[i] = uint4{0u, 0u, 0u, 0u};
    }
    // ---- stage ----
    {
        const float* src = geoms + (size_t)pb * (PMAX * 2);
        float* dst = &s_geo[0][0][0];
        for (int i = t; i < npoly * PMAX * 2; i += 256) dst[i] = src[i];
        if (t < npoly) s_len[t] = lengths[pb + t];
        for (int i = t; i < C_MID * 6; i += 256) s_w1[i] = w1[i];
        if (t < C_MID) s_b1[t] = b1[t];
    }
    __syncthreads();

    // ---- per-poly seg/cum (bitwise jnp.cumsum order) ----
    if (t < npoly) {
        int L = s_len[t];
        float cum = 0.f;
        s_cum[t][0] = 0.f;
        for (int i = 0; i < PMAX - 1; ++i) {
            float seg = 0.f;
            if (i < L - 1) {
                float dx = s_geo[t][i + 1][0] - s_geo[t][i][0];
                float dy = s_geo[t][i + 1][1] - s_geo[t][i][1];
                float sq = dx * dx + dy * dy;
                seg = (sq > 0.f) ? sqrtf(sq) : 0.f;
            }
            s_seg[t][i] = seg;
            cum += seg;
            s_cum[t][i + 1] = cum;
        }
    }
    __syncthreads();

    // ---- resample (one point per thread; duplicated across neighbor blocks, benign) ----
    const float roiw  = (float)roi_w[0], roih = (float)roi_h[0];
    const float halfx = roiw * 0.5f, halfy = roih * 0.5f;
    if (t < npoly * NUM_PTS) {
        int poly = t / NUM_PTS, j = t % NUM_PTS;
        int L = s_len[poly];
        float total = s_cum[poly][PMAX - 1];
        float px, py;
        if (total < 1e-6f) {
            px = s_geo[poly][0][0];
            py = s_geo[poly][0][1];
        } else {
            float target = total * (0.25f * (float)j);
            int idx = PMAX;
            for (int i = 0; i < PMAX; ++i) {
                if (s_cum[poly][i] >= target) { idx = i; break; }
            }
            idx = max(1, min(idx, L - 1));
            float tt = (target - s_cum[poly][idx - 1]) / (s_seg[poly][idx - 1] + 1e-8f);
            float x0 = s_geo[poly][idx - 1][0], y0 = s_geo[poly][idx - 1][1];
            px = x0 + tt * (s_geo[poly][idx][0] - x0);
            py = y0 + tt * (s_geo[poly][idx][1] - y0);
        }
        float cx = (px + halfx) / roiw;
        float cy = (py + halfy) / roih;
        s_pts[poly][j][0] = cx;
        s_pts[poly][j][1] = cy;
        float* co = out + (size_t)M_ROWS * GEO_DIM + ((size_t)(pb + poly) * NUM_PTS + j) * 2;
        co[0] = cx;
        co[1] = cy;
    }
    __syncthreads();

    // ---- conv1 (2->112) + ReLU -> bf16 A-tile slots 1..5 per poly ----
    for (int i = t; i < npoly * NUM_PTS * C_MID; i += 256) {
        int poly = i / (NUM_PTS * C_MID);
        int r = i % (NUM_PTS * C_MID);
        int p = r / C_MID;
        int c = r % C_MID;
        float acc = s_b1[c];
        const float* w = &s_w1[c * 6];
        #pragma unroll
        for (int ch = 0; ch < 2; ++ch) {
            #pragma unroll
            for (int dk = 0; dk < 3; ++dk) {
                int pp = p + dk - 1;
                float xv = (pp >= 0 && pp < NUM_PTS) ? s_pts[poly][pp][ch] : 0.f;
                acc += xv * w[ch * 3 + dk];
            }
        }
        s_A[(poly * 7 + p + 1) * C_MID + c] = f2bf(fmaxf(acc, 0.f));
    }
    __syncthreads();

    // ---- conv2 GEMM: wave w owns rows r0+16w .. +15, all 14 n-tiles ----
    const int lane = t & 63;
    const int wave = t >> 6;
    const int quad = lane >> 4;          // k-quarter for A/B frags
    const int m    = lane & 15;
    const int rw   = r0 + wave * 16;

    // A row for this lane (clamped in tail; clamped rows' stores are guarded)
    int rA = min(rw + m, M_ROWS - 1);
    int polyA = rA / NUM_PTS, pA = rA - polyA * NUM_PTS;
    const int abase = ((polyA - pb) * 7 + pA) * C_MID + quad * 8;

    f32x4 acc[NTILES];
    #pragma unroll
    for (int nt = 0; nt < NTILES; ++nt)
        #pragma unroll
        for (int i = 0; i < 4; ++i) acc[nt][i] = 0.f;

    const unsigned short* wl = Wp + lane * 8;
    #pragma unroll
    for (int ks = 0; ks < KSTEPS; ++ks) {
        short8 a = *(const short8*)(s_A + abase + ks * 32);
        #pragma unroll
        for (int nt = 0; nt < NTILES; ++nt) {
            short8 b = *(const short8*)(wl + ((ks * NTILES + nt) << 9));
            acc[nt] = __builtin_amdgcn_mfma_f32_16x16x32_bf16(a, b, acc[nt], 0, 0, 0);
        }
    }

    // ---- PE: cols 0..31 for this wave's 16 rows ----
    {
        const int col = lane & 31;
        const int d   = col >> 4;
        const int isc = (col >> 3) & 1;
        const int fr  = col & 7;
        const float pef = (float)(1 << fr) * 3.14159265358979323846f;
        #pragma unroll
        for (int it = 0; it < 8; ++it) {
            int r = rw + it * 2 + (lane >> 5);
            if (r < M_ROWS) {
                int lp = r / NUM_PTS - pb, j = r % NUM_PTS;
                float x = s_pts[lp][j][d];
                float arg = x * pef;
                float v = isc ? __cosf(arg) : __sinf(arg);
                out[(size_t)r * GEO_DIM + col] = v;
            }
        }
    }

    // ---- bias + ReLU + in-wave LayerNorm + store cols 32..255 ----
    float bias[NTILES], g[NTILES], be[NTILES];
    #pragma unroll
    for (int nt = 0; nt < NTILES; ++nt) {
        int col = nt * 16 + m;
        bias[nt] = b2[col];
        g[nt]    = gamma[col];
        be[nt]   = beta[col];
    }
    #pragma unroll
    for (int nt = 0; nt < NTILES; ++nt)
        #pragma unroll
        for (int i = 0; i < 4; ++i)
            acc[nt][i] = fmaxf(acc[nt][i] + bias[nt], 0.f);

    #pragma unroll
    for (int i = 0; i < 4; ++i) {
        float s = 0.f, q = 0.f;
        #pragma unroll
        for (int nt = 0; nt < NTILES; ++nt) {
            float v = acc[nt][i];
            s += v;
            q += v * v;
        }
        #pragma unroll
        for (int mk = 8; mk >= 1; mk >>= 1) {
            s += __shfl_xor(s, mk, 64);
            q += __shfl_xor(q, mk, 64);
        }
        float mu  = s * (1.f / C_OUT);
        float var = fmaxf(q * (1.f / C_OUT) - mu * mu, 0.f);
        float rs  = rsqrtf(var + 1e-5f);

        int r = rw + quad * 4 + i;        // C/D row = quad*4 + reg
        if (r < M_ROWS) {
            size_t ob = (size_t)r * GEO_DIM + PE_DIM + m;
            #pragma unroll
            for (int nt = 0; nt < NTILES; ++nt)
                out[ob + nt * 16] = (acc[nt][i] - mu) * rs * g[nt] + be[nt];
        }
    }
}

extern "C" void kernel_launch(void* const* d_in, const int* in_sizes, int n_in,
                              void* d_out, int out_size, void* d_ws, size_t ws_size,
                              hipStream_t stream) {
    const float* geoms   = (const float*)d_in[0];
    const int*   lengths = (const int*)d_in[1];
    const float* w1      = (const float*)d_in[2];
    const float* b1      = (const float*)d_in[3];
    const float* w2      = (const float*)d_in[4];
    const float* b2      = (const float*)d_in[5];
    const float* gamma   = (const float*)d_in[6];
    const float* beta    = (const float*)d_in[7];
    const int*   roi_w   = (const int*)d_in[8];
    const int*   roi_h   = (const int*)d_in[9];
    float* out = (float*)d_out;
    unsigned short* Wp = (unsigned short*)d_ws;   // 157696 B

    hipLaunchKernelGGL(pack_w2, dim3((WP_ELEMS + 255) / 256), dim3(256), 0, stream, w2, Wp);
    hipLaunchKernelGGL(geo_fused, dim3((M_ROWS + ROWS_B - 1) / ROWS_B), dim3(256), 0, stream,
                       geoms, lengths, w1, b1, b2, gamma, beta, roi_w, roi_h, Wp, out);
}